// Round 1
// baseline (918.652 us; speedup 1.0000x reference)
//
#include <hip/hip_runtime.h>
#include <hip/hip_bf16.h>
#include <math.h>

// Problem dims
#define B_  64
#define D_  256
#define H_  512
#define N_  16384
#define M_  64
#define S_  3
#define EPS_ 1e-4f

__device__ __forceinline__ float sigmoidf_(float x) { return 1.0f / (1.0f + expf(-x)); }

// ---------------------------------------------------------------------------
// K1/K7: head params.  One block per batch. Computes k=tanh(h@Wk^T+bk), nk,
// s=softmax(h@Ws^T+bs), beta/g/gamma from h@Wc^T+bc, and (write phase) e,a
// from h@Ww^T+bw.
// ---------------------------------------------------------------------------
template <bool WITH_W>
__global__ __launch_bounds__(256) void head_params_kernel(
    const float* __restrict__ h,
    const float* __restrict__ Wk, const float* __restrict__ bk,
    const float* __restrict__ Wc, const float* __restrict__ bc,
    const float* __restrict__ Ws, const float* __restrict__ bs,
    const float* __restrict__ Ww, const float* __restrict__ bw,
    float* __restrict__ k_out, float* __restrict__ nk_out,
    float* __restrict__ s_out,
    float* __restrict__ beta_out, float* __restrict__ g_out, float* __restrict__ gamma_out,
    float* __restrict__ e_out, float* __restrict__ a_out)
{
    const int b = blockIdx.x;
    const int tid = threadIdx.x;
    __shared__ float hs[H_];
    __shared__ float raw[198];
    for (int i = tid; i < H_; i += 256) hs[i] = h[b * H_ + i];
    __syncthreads();
    const int count = WITH_W ? 198 : 70;
    if (tid < count) {
        const float* wrow;
        float bias;
        if (tid < 64)       { wrow = Wk + tid * H_;        bias = bk[tid]; }
        else if (tid < 67)  { wrow = Wc + (tid - 64) * H_; bias = bc[tid - 64]; }
        else if (tid < 70)  { wrow = Ws + (tid - 67) * H_; bias = bs[tid - 67]; }
        else                { wrow = Ww + (tid - 70) * H_; bias = bw[tid - 70]; }
        float acc = 0.f;
        #pragma unroll 8
        for (int i = 0; i < H_; ++i) acc += wrow[i] * hs[i];
        raw[tid] = acc + bias;
    }
    __syncthreads();
    if (tid < 64) {
        float kv = tanhf(raw[tid]);
        k_out[b * 64 + tid] = kv;
        float sq = kv * kv;
        for (int off = 32; off >= 1; off >>= 1) sq += __shfl_xor(sq, off);
        if (tid == 0) nk_out[b] = sqrtf(sq) + EPS_;
    } else if (tid == 64) {
        float c0 = raw[64], c1 = raw[65], c2 = raw[66];
        beta_out[b]  = fmaxf(c0, 0.f) + EPS_;
        g_out[b]     = sigmoidf_(c1);
        gamma_out[b] = fmaxf(c2, 0.f) + 1.f + EPS_;
    } else if (tid == 65) {
        float s0 = raw[67], s1 = raw[68], s2 = raw[69];
        float mx = fmaxf(s0, fmaxf(s1, s2));
        float e0 = expf(s0 - mx), e1 = expf(s1 - mx), e2 = expf(s2 - mx);
        float inv = 1.f / (e0 + e1 + e2);
        s_out[b * 3 + 0] = e0 * inv;
        s_out[b * 3 + 1] = e1 * inv;
        s_out[b * 3 + 2] = e2 * inv;
    }
    if (WITH_W && tid >= 128 && tid < 192) {
        int m = tid - 128;
        e_out[b * 64 + m] = sigmoidf_(raw[70 + m]);
        a_out[b * 64 + m] = raw[134 + m];
    }
}

// ---------------------------------------------------------------------------
// K2/K8: dot[b,n] = k[b,:]·memory[b,n,:]  (+ optionally nM[b,n]=||mem row||+eps)
// 16 lanes per memory row (float4 each) -> fully coalesced 256B row reads.
// Block handles 64 consecutive n. Grid = B * 256.
// ---------------------------------------------------------------------------
template <bool COMPUTE_NM>
__global__ __launch_bounds__(256) void dot_kernel(
    const float* __restrict__ memory,
    const float* __restrict__ k,
    float* __restrict__ dot,
    float* __restrict__ nM)
{
    const int tid = threadIdx.x;
    const int lane = tid & 63;
    const int wid = tid >> 6;
    const int grp = lane >> 4;
    const int m16 = lane & 15;
    const int b = blockIdx.x >> 8;
    const int nbase = (blockIdx.x & 255) * 64;
    const float4 k4 = ((const float4*)(k + b * 64))[m16];
    const int slot = wid * 4 + grp;
    const size_t bbase = (size_t)b * N_;
    #pragma unroll
    for (int it = 0; it < 4; ++it) {
        const int n = nbase + it * 16 + slot;
        const float4 m4 = ((const float4*)(memory + (bbase + n) * 64))[m16];
        float d  = m4.x * k4.x + m4.y * k4.y + m4.z * k4.z + m4.w * k4.w;
        float sq = m4.x * m4.x + m4.y * m4.y + m4.z * m4.z + m4.w * m4.w;
        for (int off = 8; off >= 1; off >>= 1) {
            d += __shfl_xor(d, off);
            if (COMPUTE_NM) sq += __shfl_xor(sq, off);
        }
        if (m16 == 0) {
            dot[bbase + n] = d;
            if (COMPUTE_NM) nM[bbase + n] = sqrtf(sq) + EPS_;
        }
    }
}

// ---------------------------------------------------------------------------
// K3/K9: addressing. One block (1024 thr) per batch.
// content softmax -> interpolate -> circular 3-tap conv -> sharpen -> norm.
// dot may alias head_out (each block reads its slice before writing it).
// ---------------------------------------------------------------------------
__global__ __launch_bounds__(1024) void address_kernel(
    const float* __restrict__ dot,
    const float* __restrict__ nM,
    const float* __restrict__ w_tm1,
    const float* __restrict__ nk_a,
    const float* __restrict__ beta_a, const float* __restrict__ g_a,
    const float* __restrict__ gamma_a, const float* __restrict__ s_a,
    float* __restrict__ head_out)
{
    __shared__ float lds[N_];  // 64 KB; slots [0..16] reused as reduce scratch
    const int tid = threadIdx.x;
    const int b = blockIdx.x;
    const size_t base = (size_t)b * N_;
    const float beta = beta_a[b], g = g_a[b], gamma = gamma_a[b], nk = nk_a[b];
    const float s0 = s_a[b * 3 + 0], s1 = s_a[b * 3 + 1], s2 = s_a[b * 3 + 2];

    float lg[16];
    float lmax = -1e30f;
    #pragma unroll
    for (int t = 0; t < 16; ++t) {
        const int n = t * 1024 + tid;
        const float x = beta * dot[base + n] / (nM[base + n] * nk);
        lg[t] = x;
        lmax = fmaxf(lmax, x);
    }
    for (int off = 32; off >= 1; off >>= 1) lmax = fmaxf(lmax, __shfl_xor(lmax, off));
    if ((tid & 63) == 0) lds[tid >> 6] = lmax;
    __syncthreads();
    if (tid == 0) {
        float v = lds[0];
        for (int i = 1; i < 16; ++i) v = fmaxf(v, lds[i]);
        lds[16] = v;
    }
    __syncthreads();
    const float gmax = lds[16];

    float lsum = 0.f;
    #pragma unroll
    for (int t = 0; t < 16; ++t) { lg[t] = expf(lg[t] - gmax); lsum += lg[t]; }
    for (int off = 32; off >= 1; off >>= 1) lsum += __shfl_xor(lsum, off);
    if ((tid & 63) == 0) lds[tid >> 6] = lsum;   // distinct addresses from lds[16]
    __syncthreads();
    if (tid == 0) {
        float v = 0.f;
        for (int i = 0; i < 16; ++i) v += lds[i];
        lds[16] = v;
    }
    __syncthreads();
    const float inv_sum = 1.f / lds[16];
    __syncthreads();  // everyone has read scratch before we fill lds with inter

    #pragma unroll
    for (int t = 0; t < 16; ++t) {
        const int n = t * 1024 + tid;
        lds[n] = g * lg[t] * inv_sum + (1.f - g) * w_tm1[base + n];
    }
    __syncthreads();

    float sh[16];
    float lsum2 = 0.f;
    #pragma unroll
    for (int t = 0; t < 16; ++t) {
        const int n = t * 1024 + tid;
        const float conv = s2 * lds[n] + s1 * lds[(n + N_ - 1) & (N_ - 1)]
                         + s0 * lds[(n + N_ - 2) & (N_ - 1)];
        const float v = powf(fmaxf(conv, 1e-8f), gamma);
        sh[t] = v;
        lsum2 += v;
    }
    __syncthreads();  // all conv reads done; scratch reuse safe
    for (int off = 32; off >= 1; off >>= 1) lsum2 += __shfl_xor(lsum2, off);
    if ((tid & 63) == 0) lds[tid >> 6] = lsum2;
    __syncthreads();
    if (tid == 0) {
        float v = 0.f;
        for (int i = 0; i < 16; ++i) v += lds[i];
        lds[16] = v;
    }
    __syncthreads();
    const float inv2 = 1.f / lds[16];
    #pragma unroll
    for (int t = 0; t < 16; ++t) head_out[base + t * 1024 + tid] = sh[t] * inv2;
}

// ---------------------------------------------------------------------------
// K4: M_read[b,m] = sum_n head[b,n] * memory[b,n,m].  Partial per block,
// atomicAdd finish. Grid = B * 64 (256 n per block). M_read pre-zeroed.
// ---------------------------------------------------------------------------
__global__ __launch_bounds__(256) void m_read_kernel(
    const float* __restrict__ memory,
    const float* __restrict__ head,
    float* __restrict__ M_read)
{
    const int tid = threadIdx.x;
    const int lane = tid & 63;
    const int wid = tid >> 6;
    const int grp = lane >> 4;
    const int m16 = lane & 15;
    const int b = blockIdx.x >> 6;
    const int nbase = (blockIdx.x & 63) * 256;
    const int slot = wid * 4 + grp;
    const size_t bbase = (size_t)b * N_;
    float4 acc = make_float4(0.f, 0.f, 0.f, 0.f);
    #pragma unroll 4
    for (int it = 0; it < 16; ++it) {
        const int n = nbase + it * 16 + slot;
        const float w = head[bbase + n];
        const float4 m4 = ((const float4*)(memory + (bbase + n) * 64))[m16];
        acc.x += w * m4.x; acc.y += w * m4.y; acc.z += w * m4.z; acc.w += w * m4.w;
    }
    for (int off = 32; off >= 16; off >>= 1) {
        acc.x += __shfl_xor(acc.x, off);
        acc.y += __shfl_xor(acc.y, off);
        acc.z += __shfl_xor(acc.z, off);
        acc.w += __shfl_xor(acc.w, off);
    }
    __shared__ float4 part[64];
    if (lane < 16) part[wid * 16 + lane] = acc;
    __syncthreads();
    if (tid < 16) {
        float4 t = part[tid];
        for (int w = 1; w < 4; ++w) {
            const float4 p = part[w * 16 + tid];
            t.x += p.x; t.y += p.y; t.z += p.z; t.w += p.w;
        }
        atomicAdd(&M_read[b * 64 + tid * 4 + 0], t.x);
        atomicAdd(&M_read[b * 64 + tid * 4 + 1], t.y);
        atomicAdd(&M_read[b * 64 + tid * 4 + 2], t.z);
        atomicAdd(&M_read[b * 64 + tid * 4 + 3], t.w);
    }
}

// ---------------------------------------------------------------------------
// K5: gates[b,j] = [inp|M_read|h_tm1]·[W_ih|W_hh][j,:] + b_ih[j] + b_hh[j]
// Tiled fp32 GEMM: 64x64 tile per block, K=832 in steps of 32. Grid = 32.
// ---------------------------------------------------------------------------
__global__ __launch_bounds__(256) void gates_kernel(
    const float* __restrict__ inp,
    const float* __restrict__ M_read,
    const float* __restrict__ h_tm1,
    const float* __restrict__ W_ih, const float* __restrict__ b_ih,
    const float* __restrict__ W_hh, const float* __restrict__ b_hh,
    float* __restrict__ gates)
{
    __shared__ __align__(16) float Asm[32][68];
    __shared__ __align__(16) float Bsm[32][68];
    const int tid = threadIdx.x;
    const int tx = tid & 15, ty = tid >> 4;
    const int jbase = blockIdx.x * 64;
    float acc[4][4] = {};
    for (int k0 = 0; k0 < 832; k0 += 32) {
        #pragma unroll
        for (int i = 0; i < 8; ++i) {
            const int e = i * 256 + tid;
            const int kk = e & 31, bb = e >> 5;
            const int kg = k0 + kk;
            float v;
            if (kg < 256)      v = inp[bb * 256 + kg];
            else if (kg < 320) v = M_read[bb * 64 + kg - 256];
            else               v = h_tm1[bb * 512 + kg - 320];
            Asm[kk][bb] = v;
            const int jj = bb;
            const int jg = jbase + jj;
            float w;
            if (kg < 320) w = W_ih[jg * 320 + kg];
            else          w = W_hh[jg * 512 + kg - 320];
            Bsm[kk][jj] = w;
        }
        __syncthreads();
        #pragma unroll
        for (int k = 0; k < 32; ++k) {
            const float4 av = *((const float4*)&Asm[k][ty * 4]);
            const float4 wv = *((const float4*)&Bsm[k][tx * 4]);
            acc[0][0] += av.x * wv.x; acc[0][1] += av.x * wv.y; acc[0][2] += av.x * wv.z; acc[0][3] += av.x * wv.w;
            acc[1][0] += av.y * wv.x; acc[1][1] += av.y * wv.y; acc[1][2] += av.y * wv.z; acc[1][3] += av.y * wv.w;
            acc[2][0] += av.z * wv.x; acc[2][1] += av.z * wv.y; acc[2][2] += av.z * wv.z; acc[2][3] += av.z * wv.w;
            acc[3][0] += av.w * wv.x; acc[3][1] += av.w * wv.y; acc[3][2] += av.w * wv.z; acc[3][3] += av.w * wv.w;
        }
        __syncthreads();
    }
    #pragma unroll
    for (int bi = 0; bi < 4; ++bi) {
        const int b = ty * 4 + bi;
        #pragma unroll
        for (int ji = 0; ji < 4; ++ji) {
            const int j = jbase + tx * 4 + ji;
            gates[b * 2048 + j] = acc[bi][ji] + b_ih[j] + b_hh[j];
        }
    }
}

// ---------------------------------------------------------------------------
// K6: LSTM elementwise.
// ---------------------------------------------------------------------------
__global__ __launch_bounds__(256) void lstm_kernel(
    const float* __restrict__ gates,
    const float* __restrict__ c_tm1,
    float* __restrict__ h_out, float* __restrict__ c_out)
{
    const int idx = blockIdx.x * 256 + threadIdx.x;  // B*H
    const int b = idx >> 9, j = idx & 511;
    const float* gr = gates + b * 2048;
    const float i_ = sigmoidf_(gr[j]);
    const float f_ = sigmoidf_(gr[512 + j]);
    const float g_ = tanhf(gr[1024 + j]);
    const float o_ = sigmoidf_(gr[1536 + j]);
    const float c = f_ * c_tm1[idx] + i_ * g_;
    c_out[idx] = c;
    h_out[idx] = o_ * tanhf(c);
}

// ---------------------------------------------------------------------------
// K10: M_out = memory*(1 - ww*e) + ww*a
// ---------------------------------------------------------------------------
__global__ __launch_bounds__(256) void m_out_kernel(
    const float* __restrict__ memory,
    const float* __restrict__ whead,
    const float* __restrict__ e,
    const float* __restrict__ a,
    float* __restrict__ M_out)
{
    const size_t total = (size_t)B_ * N_ * 16;  // float4 count
    const size_t stride = (size_t)gridDim.x * 256;
    for (size_t idx = (size_t)blockIdx.x * 256 + threadIdx.x; idx < total; idx += stride) {
        const size_t nlin = idx >> 4;
        const int m4 = (int)(idx & 15);
        const int b = (int)(nlin >> 14);
        const float w = whead[nlin];
        const float4 ev = ((const float4*)(e + b * 64))[m4];
        const float4 av = ((const float4*)(a + b * 64))[m4];
        const float4 mv = ((const float4*)memory)[idx];
        float4 o;
        o.x = mv.x * (1.f - w * ev.x) + w * av.x;
        o.y = mv.y * (1.f - w * ev.y) + w * av.y;
        o.z = mv.z * (1.f - w * ev.z) + w * av.z;
        o.w = mv.w * (1.f - w * ev.w) + w * av.w;
        ((float4*)M_out)[idx] = o;
    }
}

// ---------------------------------------------------------------------------
extern "C" void kernel_launch(void* const* d_in, const int* in_sizes, int n_in,
                              void* d_out, int out_size, void* d_ws, size_t ws_size,
                              hipStream_t stream)
{
    const float* inp       = (const float*)d_in[0];
    const float* h_tm1     = (const float*)d_in[1];
    const float* c_tm1     = (const float*)d_in[2];
    const float* read_tm1  = (const float*)d_in[3];
    const float* write_tm1 = (const float*)d_in[4];
    const float* memory    = (const float*)d_in[5];
    const float* W_ih = (const float*)d_in[6];  const float* b_ih = (const float*)d_in[7];
    const float* W_hh = (const float*)d_in[8];  const float* b_hh = (const float*)d_in[9];
    const float* W_rk = (const float*)d_in[10]; const float* b_rk = (const float*)d_in[11];
    const float* W_wk = (const float*)d_in[12]; const float* b_wk = (const float*)d_in[13];
    const float* W_rc = (const float*)d_in[14]; const float* b_rc = (const float*)d_in[15];
    const float* W_wc = (const float*)d_in[16]; const float* b_wc = (const float*)d_in[17];
    const float* W_rs = (const float*)d_in[18]; const float* b_rs = (const float*)d_in[19];
    const float* W_ws = (const float*)d_in[20]; const float* b_ws = (const float*)d_in[21];
    const float* W_w  = (const float*)d_in[22]; const float* b_w  = (const float*)d_in[23];

    float* out = (float*)d_out;
    float* h_out   = out;                       // B*H
    float* c_out   = out + 32768;               // B*H
    float* rhead   = out + 65536;               // B*N
    float* whead   = out + 65536 + 1048576;     // B*N
    float* Mout    = out + 65536 + 2 * 1048576; // B*N*M

    // Big scratch aliased into d_out regions that are written later:
    float* dot_r = rhead;   // consumed (per-b slice) by address_kernel before overwrite
    float* dot_w = whead;
    float* nM    = Mout;    // first B*N floats of M_out region; overwritten by K10

    // Small scratch in workspace
    float* ws = (float*)d_ws;
    float* gates  = ws;             // 131072
    float* rk     = ws + 131072;    // 4096
    float* wk     = ws + 135168;    // 4096
    float* M_read = ws + 139264;    // 4096
    float* e_buf  = ws + 143360;    // 4096
    float* a_buf  = ws + 147456;    // 4096
    float* rs     = ws + 151552;    // 192
    float* wss    = ws + 151744;    // 192
    float* rbeta  = ws + 151936;
    float* rg     = ws + 152000;
    float* rgamma = ws + 152064;
    float* rnk    = ws + 152128;
    float* wbeta  = ws + 152192;
    float* wg     = ws + 152256;
    float* wgamma = ws + 152320;
    float* wnk    = ws + 152384;

    hipMemsetAsync(M_read, 0, B_ * M_ * sizeof(float), stream);

    // 1. read-head params from h_tm1
    head_params_kernel<false><<<B_, 256, 0, stream>>>(
        h_tm1, W_rk, b_rk, W_rc, b_rc, W_rs, b_rs, nullptr, nullptr,
        rk, rnk, rs, rbeta, rg, rgamma, nullptr, nullptr);
    // 2. read dot + norms (memory pass 1)
    dot_kernel<true><<<B_ * 256, 256, 0, stream>>>(memory, rk, dot_r, nM);
    // 3. read addressing -> read_head
    address_kernel<<<B_, 1024, 0, stream>>>(dot_r, nM, read_tm1, rnk, rbeta, rg, rgamma, rs, rhead);
    // 4. M_read (memory pass 2)
    m_read_kernel<<<B_ * 64, 256, 0, stream>>>(memory, rhead, M_read);
    // 5. LSTM gates GEMM
    gates_kernel<<<32, 256, 0, stream>>>(inp, M_read, h_tm1, W_ih, b_ih, W_hh, b_hh, gates);
    // 6. LSTM elementwise -> h_t, c_t
    lstm_kernel<<<128, 256, 0, stream>>>(gates, c_tm1, h_out, c_out);
    // 7. write-head params from h_t (incl. erase/add vectors)
    head_params_kernel<true><<<B_, 256, 0, stream>>>(
        h_out, W_wk, b_wk, W_wc, b_wc, W_ws, b_ws, W_w, b_w,
        wk, wnk, wss, wbeta, wg, wgamma, e_buf, a_buf);
    // 8. write dot (memory pass 3; reuse nM)
    dot_kernel<false><<<B_ * 256, 256, 0, stream>>>(memory, wk, dot_w, nullptr);
    // 9. write addressing -> write_head
    address_kernel<<<B_, 1024, 0, stream>>>(dot_w, nM, write_tm1, wnk, wbeta, wg, wgamma, wss, whead);
    // 10. M_out (memory pass 4: read + write)
    m_out_kernel<<<16384, 256, 0, stream>>>(memory, whead, e_buf, a_buf, Mout);
}

// Round 2
// 785.796 us; speedup vs baseline: 1.1691x; 1.1691x over previous
//
#include <hip/hip_runtime.h>
#include <hip/hip_bf16.h>
#include <math.h>

// Problem dims
#define B_  64
#define D_  256
#define H_  512
#define N_  16384
#define M_  64
#define S_  3
#define EPS_ 1e-4f

__device__ __forceinline__ float sigmoidf_(float x) { return 1.0f / (1.0f + expf(-x)); }

// ---------------------------------------------------------------------------
// K1/K7: head params.  One block per batch, 4 waves. Wave-per-row GEMV:
// lane l holds h[l+64j] (j<8); each wave reduces rows r = wid, wid+4, ...
// with coalesced loads + 64-lane shuffle reduce.
// ---------------------------------------------------------------------------
template <bool WITH_W>
__global__ __launch_bounds__(256) void head_params_kernel(
    const float* __restrict__ h,
    const float* __restrict__ Wk, const float* __restrict__ bk,
    const float* __restrict__ Wc, const float* __restrict__ bc,
    const float* __restrict__ Ws, const float* __restrict__ bs,
    const float* __restrict__ Ww, const float* __restrict__ bw,
    float* __restrict__ k_out, float* __restrict__ nk_out,
    float* __restrict__ s_out,
    float* __restrict__ beta_out, float* __restrict__ g_out, float* __restrict__ gamma_out,
    float* __restrict__ e_out, float* __restrict__ a_out)
{
    const int b = blockIdx.x;
    const int tid = threadIdx.x;
    const int lane = tid & 63;
    const int wid = tid >> 6;
    __shared__ float raw[198];

    float h8[8];
    #pragma unroll
    for (int j = 0; j < 8; ++j) h8[j] = h[b * H_ + lane + 64 * j];

    const int count = WITH_W ? 198 : 70;
    for (int r = wid; r < count; r += 4) {
        const float* wrow;
        float bias;
        if (r < 64)       { wrow = Wk + r * H_;        bias = bk[r]; }
        else if (r < 67)  { wrow = Wc + (r - 64) * H_; bias = bc[r - 64]; }
        else if (r < 70)  { wrow = Ws + (r - 67) * H_; bias = bs[r - 67]; }
        else              { wrow = Ww + (r - 70) * H_; bias = bw[r - 70]; }
        float acc = 0.f;
        #pragma unroll
        for (int j = 0; j < 8; ++j) acc += wrow[lane + 64 * j] * h8[j];
        for (int off = 32; off >= 1; off >>= 1) acc += __shfl_xor(acc, off);
        if (lane == 0) raw[r] = acc + bias;
    }
    __syncthreads();

    if (tid < 64) {
        float kv = tanhf(raw[tid]);
        k_out[b * 64 + tid] = kv;
        float sq = kv * kv;
        for (int off = 32; off >= 1; off >>= 1) sq += __shfl_xor(sq, off);
        if (tid == 0) nk_out[b] = sqrtf(sq) + EPS_;
    } else if (tid == 64) {
        float c0 = raw[64], c1 = raw[65], c2 = raw[66];
        beta_out[b]  = fmaxf(c0, 0.f) + EPS_;
        g_out[b]     = sigmoidf_(c1);
        gamma_out[b] = fmaxf(c2, 0.f) + 1.f + EPS_;
    } else if (tid == 65) {
        float s0 = raw[67], s1 = raw[68], s2 = raw[69];
        float mx = fmaxf(s0, fmaxf(s1, s2));
        float e0 = expf(s0 - mx), e1 = expf(s1 - mx), e2 = expf(s2 - mx);
        float inv = 1.f / (e0 + e1 + e2);
        s_out[b * 3 + 0] = e0 * inv;
        s_out[b * 3 + 1] = e1 * inv;
        s_out[b * 3 + 2] = e2 * inv;
    }
    if (WITH_W && tid >= 128 && tid < 192) {
        int m = tid - 128;
        e_out[b * 64 + m] = sigmoidf_(raw[70 + m]);
        a_out[b * 64 + m] = raw[134 + m];
    }
}

// ---------------------------------------------------------------------------
// K2/K8: dot[b,n] = k[b,:]·memory[b,n,:]  (+ optionally nM[b,n]=||mem row||+eps)
// 16 lanes per memory row (float4 each) -> fully coalesced 256B row reads.
// Block handles 64 consecutive n. Grid = B * 256.
// ---------------------------------------------------------------------------
template <bool COMPUTE_NM>
__global__ __launch_bounds__(256) void dot_kernel(
    const float* __restrict__ memory,
    const float* __restrict__ k,
    float* __restrict__ dot,
    float* __restrict__ nM)
{
    const int tid = threadIdx.x;
    const int lane = tid & 63;
    const int wid = tid >> 6;
    const int grp = lane >> 4;
    const int m16 = lane & 15;
    const int b = blockIdx.x >> 8;
    const int nbase = (blockIdx.x & 255) * 64;
    const float4 k4 = ((const float4*)(k + b * 64))[m16];
    const int slot = wid * 4 + grp;
    const size_t bbase = (size_t)b * N_;
    #pragma unroll
    for (int it = 0; it < 4; ++it) {
        const int n = nbase + it * 16 + slot;
        const float4 m4 = ((const float4*)(memory + (bbase + n) * 64))[m16];
        float d  = m4.x * k4.x + m4.y * k4.y + m4.z * k4.z + m4.w * k4.w;
        float sq = m4.x * m4.x + m4.y * m4.y + m4.z * m4.z + m4.w * m4.w;
        for (int off = 8; off >= 1; off >>= 1) {
            d += __shfl_xor(d, off);
            if (COMPUTE_NM) sq += __shfl_xor(sq, off);
        }
        if (m16 == 0) {
            dot[bbase + n] = d;
            if (COMPUTE_NM) nM[bbase + n] = sqrtf(sq) + EPS_;
        }
    }
}

// ---------------------------------------------------------------------------
// K3/K9: addressing. One block (1024 thr) per batch.
// content softmax -> interpolate -> circular 3-tap conv -> sharpen -> norm.
// dot may alias head_out (each block reads its slice before writing it).
// ---------------------------------------------------------------------------
__global__ __launch_bounds__(1024) void address_kernel(
    const float* __restrict__ dot,
    const float* __restrict__ nM,
    const float* __restrict__ w_tm1,
    const float* __restrict__ nk_a,
    const float* __restrict__ beta_a, const float* __restrict__ g_a,
    const float* __restrict__ gamma_a, const float* __restrict__ s_a,
    float* __restrict__ head_out)
{
    __shared__ float lds[N_];  // 64 KB; slots [0..16] reused as reduce scratch
    const int tid = threadIdx.x;
    const int b = blockIdx.x;
    const size_t base = (size_t)b * N_;
    const float beta = beta_a[b], g = g_a[b], gamma = gamma_a[b], nk = nk_a[b];
    const float s0 = s_a[b * 3 + 0], s1 = s_a[b * 3 + 1], s2 = s_a[b * 3 + 2];

    float lg[16];
    float lmax = -1e30f;
    #pragma unroll
    for (int t = 0; t < 16; ++t) {
        const int n = t * 1024 + tid;
        const float x = beta * dot[base + n] / (nM[base + n] * nk);
        lg[t] = x;
        lmax = fmaxf(lmax, x);
    }
    for (int off = 32; off >= 1; off >>= 1) lmax = fmaxf(lmax, __shfl_xor(lmax, off));
    if ((tid & 63) == 0) lds[tid >> 6] = lmax;
    __syncthreads();
    if (tid == 0) {
        float v = lds[0];
        for (int i = 1; i < 16; ++i) v = fmaxf(v, lds[i]);
        lds[16] = v;
    }
    __syncthreads();
    const float gmax = lds[16];

    float lsum = 0.f;
    #pragma unroll
    for (int t = 0; t < 16; ++t) { lg[t] = expf(lg[t] - gmax); lsum += lg[t]; }
    for (int off = 32; off >= 1; off >>= 1) lsum += __shfl_xor(lsum, off);
    if ((tid & 63) == 0) lds[tid >> 6] = lsum;
    __syncthreads();
    if (tid == 0) {
        float v = 0.f;
        for (int i = 0; i < 16; ++i) v += lds[i];
        lds[16] = v;
    }
    __syncthreads();
    const float inv_sum = 1.f / lds[16];
    __syncthreads();  // everyone has read scratch before we fill lds with inter

    #pragma unroll
    for (int t = 0; t < 16; ++t) {
        const int n = t * 1024 + tid;
        lds[n] = g * lg[t] * inv_sum + (1.f - g) * w_tm1[base + n];
    }
    __syncthreads();

    float sh[16];
    float lsum2 = 0.f;
    #pragma unroll
    for (int t = 0; t < 16; ++t) {
        const int n = t * 1024 + tid;
        const float conv = s2 * lds[n] + s1 * lds[(n + N_ - 1) & (N_ - 1)]
                         + s0 * lds[(n + N_ - 2) & (N_ - 1)];
        const float v = powf(fmaxf(conv, 1e-8f), gamma);
        sh[t] = v;
        lsum2 += v;
    }
    __syncthreads();  // all conv reads done; scratch reuse safe
    for (int off = 32; off >= 1; off >>= 1) lsum2 += __shfl_xor(lsum2, off);
    if ((tid & 63) == 0) lds[tid >> 6] = lsum2;
    __syncthreads();
    if (tid == 0) {
        float v = 0.f;
        for (int i = 0; i < 16; ++i) v += lds[i];
        lds[16] = v;
    }
    __syncthreads();
    const float inv2 = 1.f / lds[16];
    #pragma unroll
    for (int t = 0; t < 16; ++t) head_out[base + t * 1024 + tid] = sh[t] * inv2;
}

// ---------------------------------------------------------------------------
// K4: M_read[b,m] = sum_n head[b,n] * memory[b,n,m].  Partial per block,
// atomicAdd finish. Grid = B * 64 (256 n per block). M_read pre-zeroed.
// ---------------------------------------------------------------------------
__global__ __launch_bounds__(256) void m_read_kernel(
    const float* __restrict__ memory,
    const float* __restrict__ head,
    float* __restrict__ M_read)
{
    const int tid = threadIdx.x;
    const int lane = tid & 63;
    const int wid = tid >> 6;
    const int grp = lane >> 4;
    const int m16 = lane & 15;
    const int b = blockIdx.x >> 6;
    const int nbase = (blockIdx.x & 63) * 256;
    const int slot = wid * 4 + grp;
    const size_t bbase = (size_t)b * N_;
    float4 acc = make_float4(0.f, 0.f, 0.f, 0.f);
    #pragma unroll 4
    for (int it = 0; it < 16; ++it) {
        const int n = nbase + it * 16 + slot;
        const float w = head[bbase + n];
        const float4 m4 = ((const float4*)(memory + (bbase + n) * 64))[m16];
        acc.x += w * m4.x; acc.y += w * m4.y; acc.z += w * m4.z; acc.w += w * m4.w;
    }
    for (int off = 32; off >= 16; off >>= 1) {
        acc.x += __shfl_xor(acc.x, off);
        acc.y += __shfl_xor(acc.y, off);
        acc.z += __shfl_xor(acc.z, off);
        acc.w += __shfl_xor(acc.w, off);
    }
    __shared__ float4 part[64];
    if (lane < 16) part[wid * 16 + lane] = acc;
    __syncthreads();
    if (tid < 16) {
        float4 t = part[tid];
        for (int w = 1; w < 4; ++w) {
            const float4 p = part[w * 16 + tid];
            t.x += p.x; t.y += p.y; t.z += p.z; t.w += p.w;
        }
        atomicAdd(&M_read[b * 64 + tid * 4 + 0], t.x);
        atomicAdd(&M_read[b * 64 + tid * 4 + 1], t.y);
        atomicAdd(&M_read[b * 64 + tid * 4 + 2], t.z);
        atomicAdd(&M_read[b * 64 + tid * 4 + 3], t.w);
    }
}

// ---------------------------------------------------------------------------
// K5: gates split-K GEMM.  gates[b,j] += x[b,k]·W[j,k] over one 64-wide
// K-chunk.  x = [inp | M_read | h_tm1] (832 = 13 chunks of 64; chunks 0-3 =
// inp, 4 = M_read, 5-12 = h_tm1).  Grid = 13 chunks * 32 j-tiles = 416
// blocks; 64b x 64j tile, 4x4 register blocking; atomicAdd epilogue into
// pre-zeroed gates. Biases added in lstm_kernel.
// ---------------------------------------------------------------------------
__global__ __launch_bounds__(256) void gates_splitk_kernel(
    const float* __restrict__ inp,
    const float* __restrict__ M_read,
    const float* __restrict__ h_tm1,
    const float* __restrict__ W_ih,
    const float* __restrict__ W_hh,
    float* __restrict__ gates)
{
    __shared__ __align__(16) float Xsm[64][68];
    __shared__ __align__(16) float Wsm[64][68];
    const int tid = threadIdx.x;
    const int jb = blockIdx.x & 31;
    const int c  = blockIdx.x >> 5;      // K-chunk 0..12
    const int j0 = jb * 64;

    // Stage X chunk (64 b x 64 k) and W chunk (64 j x 64 k), transposed to
    // [k][b]/[k][j].  float4 global loads, coalesced.
    #pragma unroll
    for (int i = 0; i < 4; ++i) {
        const int e = i * 256 + tid;     // float4 index 0..1023
        const int row = e >> 4;          // b
        const int c4 = e & 15;
        const float* xrow;
        if (c < 4)       xrow = inp    + row * 256 + c * 64;
        else if (c == 4) xrow = M_read + row * 64;
        else             xrow = h_tm1  + row * 512 + (c - 5) * 64;
        const float4 v = ((const float4*)xrow)[c4];
        const int kl = c4 * 4;
        Xsm[kl + 0][row] = v.x; Xsm[kl + 1][row] = v.y;
        Xsm[kl + 2][row] = v.z; Xsm[kl + 3][row] = v.w;
    }
    #pragma unroll
    for (int i = 0; i < 4; ++i) {
        const int e = i * 256 + tid;
        const int row = e >> 4;          // j local
        const int c4 = e & 15;
        const float* wrow;
        if (c < 5) wrow = W_ih + (j0 + row) * 320 + c * 64;
        else       wrow = W_hh + (j0 + row) * 512 + (c - 5) * 64;
        const float4 v = ((const float4*)wrow)[c4];
        const int kl = c4 * 4;
        Wsm[kl + 0][row] = v.x; Wsm[kl + 1][row] = v.y;
        Wsm[kl + 2][row] = v.z; Wsm[kl + 3][row] = v.w;
    }
    __syncthreads();

    const int tx = tid & 15, ty = tid >> 4;
    float acc[4][4] = {};
    #pragma unroll
    for (int k = 0; k < 64; ++k) {
        const float4 av = *((const float4*)&Xsm[k][ty * 4]);
        const float4 wv = *((const float4*)&Wsm[k][tx * 4]);
        acc[0][0] += av.x * wv.x; acc[0][1] += av.x * wv.y; acc[0][2] += av.x * wv.z; acc[0][3] += av.x * wv.w;
        acc[1][0] += av.y * wv.x; acc[1][1] += av.y * wv.y; acc[1][2] += av.y * wv.z; acc[1][3] += av.y * wv.w;
        acc[2][0] += av.z * wv.x; acc[2][1] += av.z * wv.y; acc[2][2] += av.z * wv.z; acc[2][3] += av.z * wv.w;
        acc[3][0] += av.w * wv.x; acc[3][1] += av.w * wv.y; acc[3][2] += av.w * wv.z; acc[3][3] += av.w * wv.w;
    }
    #pragma unroll
    for (int bi = 0; bi < 4; ++bi) {
        const int b = ty * 4 + bi;
        #pragma unroll
        for (int ji = 0; ji < 4; ++ji) {
            atomicAdd(&gates[b * 2048 + j0 + tx * 4 + ji], acc[bi][ji]);
        }
    }
}

// ---------------------------------------------------------------------------
// K6: LSTM elementwise (biases folded in here).
// ---------------------------------------------------------------------------
__global__ __launch_bounds__(256) void lstm_kernel(
    const float* __restrict__ gates,
    const float* __restrict__ b_ih, const float* __restrict__ b_hh,
    const float* __restrict__ c_tm1,
    float* __restrict__ h_out, float* __restrict__ c_out)
{
    const int idx = blockIdx.x * 256 + threadIdx.x;  // B*H
    const int b = idx >> 9, j = idx & 511;
    const float* gr = gates + b * 2048;
    const float i_ = sigmoidf_(gr[j]        + b_ih[j]        + b_hh[j]);
    const float f_ = sigmoidf_(gr[512 + j]  + b_ih[512 + j]  + b_hh[512 + j]);
    const float g_ = tanhf(   gr[1024 + j] + b_ih[1024 + j] + b_hh[1024 + j]);
    const float o_ = sigmoidf_(gr[1536 + j] + b_ih[1536 + j] + b_hh[1536 + j]);
    const float c = f_ * c_tm1[idx] + i_ * g_;
    c_out[idx] = c;
    h_out[idx] = o_ * tanhf(c);
}

// ---------------------------------------------------------------------------
// K10: M_out = memory*(1 - ww*e) + ww*a
// ---------------------------------------------------------------------------
__global__ __launch_bounds__(256) void m_out_kernel(
    const float* __restrict__ memory,
    const float* __restrict__ whead,
    const float* __restrict__ e,
    const float* __restrict__ a,
    float* __restrict__ M_out)
{
    const size_t total = (size_t)B_ * N_ * 16;  // float4 count
    const size_t stride = (size_t)gridDim.x * 256;
    for (size_t idx = (size_t)blockIdx.x * 256 + threadIdx.x; idx < total; idx += stride) {
        const size_t nlin = idx >> 4;
        const int m4 = (int)(idx & 15);
        const int b = (int)(nlin >> 14);
        const float w = whead[nlin];
        const float4 ev = ((const float4*)(e + b * 64))[m4];
        const float4 av = ((const float4*)(a + b * 64))[m4];
        const float4 mv = ((const float4*)memory)[idx];
        float4 o;
        o.x = mv.x * (1.f - w * ev.x) + w * av.x;
        o.y = mv.y * (1.f - w * ev.y) + w * av.y;
        o.z = mv.z * (1.f - w * ev.z) + w * av.z;
        o.w = mv.w * (1.f - w * ev.w) + w * av.w;
        ((float4*)M_out)[idx] = o;
    }
}

// ---------------------------------------------------------------------------
extern "C" void kernel_launch(void* const* d_in, const int* in_sizes, int n_in,
                              void* d_out, int out_size, void* d_ws, size_t ws_size,
                              hipStream_t stream)
{
    const float* inp       = (const float*)d_in[0];
    const float* h_tm1     = (const float*)d_in[1];
    const float* c_tm1     = (const float*)d_in[2];
    const float* read_tm1  = (const float*)d_in[3];
    const float* write_tm1 = (const float*)d_in[4];
    const float* memory    = (const float*)d_in[5];
    const float* W_ih = (const float*)d_in[6];  const float* b_ih = (const float*)d_in[7];
    const float* W_hh = (const float*)d_in[8];  const float* b_hh = (const float*)d_in[9];
    const float* W_rk = (const float*)d_in[10]; const float* b_rk = (const float*)d_in[11];
    const float* W_wk = (const float*)d_in[12]; const float* b_wk = (const float*)d_in[13];
    const float* W_rc = (const float*)d_in[14]; const float* b_rc = (const float*)d_in[15];
    const float* W_wc = (const float*)d_in[16]; const float* b_wc = (const float*)d_in[17];
    const float* W_rs = (const float*)d_in[18]; const float* b_rs = (const float*)d_in[19];
    const float* W_ws = (const float*)d_in[20]; const float* b_ws = (const float*)d_in[21];
    const float* W_w  = (const float*)d_in[22]; const float* b_w  = (const float*)d_in[23];

    float* out = (float*)d_out;
    float* h_out   = out;                       // B*H
    float* c_out   = out + 32768;               // B*H
    float* rhead   = out + 65536;               // B*N
    float* whead   = out + 65536 + 1048576;     // B*N
    float* Mout    = out + 65536 + 2 * 1048576; // B*N*M

    // Big scratch aliased into d_out regions that are written later:
    float* dot_r = rhead;   // consumed (per-b slice) by address_kernel before overwrite
    float* dot_w = whead;
    float* nM    = Mout;    // first B*N floats of M_out region; overwritten by K10

    // Small scratch in workspace
    float* ws = (float*)d_ws;
    float* gates  = ws;             // 131072
    float* rk     = ws + 131072;    // 4096
    float* wk     = ws + 135168;    // 4096
    float* M_read = ws + 139264;    // 4096
    float* e_buf  = ws + 143360;    // 4096
    float* a_buf  = ws + 147456;    // 4096
    float* rs     = ws + 151552;    // 192
    float* wss    = ws + 151744;    // 192
    float* rbeta  = ws + 151936;
    float* rg     = ws + 152000;
    float* rgamma = ws + 152064;
    float* rnk    = ws + 152128;
    float* wbeta  = ws + 152192;
    float* wg     = ws + 152256;
    float* wgamma = ws + 152320;
    float* wnk    = ws + 152384;

    hipMemsetAsync(M_read, 0, B_ * M_ * sizeof(float), stream);
    hipMemsetAsync(gates, 0, B_ * 4 * H_ * sizeof(float), stream);

    // 1. read-head params from h_tm1
    head_params_kernel<false><<<B_, 256, 0, stream>>>(
        h_tm1, W_rk, b_rk, W_rc, b_rc, W_rs, b_rs, nullptr, nullptr,
        rk, rnk, rs, rbeta, rg, rgamma, nullptr, nullptr);
    // 2. read dot + norms (memory pass 1)
    dot_kernel<true><<<B_ * 256, 256, 0, stream>>>(memory, rk, dot_r, nM);
    // 3. read addressing -> read_head
    address_kernel<<<B_, 1024, 0, stream>>>(dot_r, nM, read_tm1, rnk, rbeta, rg, rgamma, rs, rhead);
    // 4. M_read (memory pass 2)
    m_read_kernel<<<B_ * 64, 256, 0, stream>>>(memory, rhead, M_read);
    // 5. LSTM gates split-K GEMM (416 blocks)
    gates_splitk_kernel<<<13 * 32, 256, 0, stream>>>(inp, M_read, h_tm1, W_ih, W_hh, gates);
    // 6. LSTM elementwise -> h_t, c_t
    lstm_kernel<<<128, 256, 0, stream>>>(gates, b_ih, b_hh, c_tm1, h_out, c_out);
    // 7. write-head params from h_t (incl. erase/add vectors)
    head_params_kernel<true><<<B_, 256, 0, stream>>>(
        h_out, W_wk, b_wk, W_wc, b_wc, W_ws, b_ws, W_w, b_w,
        wk, wnk, wss, wbeta, wg, wgamma, e_buf, a_buf);
    // 8. write dot (memory pass 3; reuse nM)
    dot_kernel<false><<<B_ * 256, 256, 0, stream>>>(memory, wk, dot_w, nullptr);
    // 9. write addressing -> write_head
    address_kernel<<<B_, 1024, 0, stream>>>(dot_w, nM, write_tm1, wnk, wbeta, wg, wgamma, wss, whead);
    // 10. M_out (memory pass 4: read + write)
    m_out_kernel<<<16384, 256, 0, stream>>>(memory, whead, e_buf, a_buf, Mout);
}